// Round 3
// baseline (156.904 us; speedup 1.0000x reference)
//
#include <hip/hip_runtime.h>

// RegionPartitioner: x (8,4,500,500) f32, step=32, region=64, edge-pad to 512.
// Out: (8, 225, 4, 64, 64) f32.  out[b,r,c,rr,rc] = x[b,c,min(32*(r/15)+rr,499),
//                                                      min(32*(r%15)+rc,499)]
//
// R2 changes vs R1:
//  - XCD-aware swizzle: b = blockIdx & 7 (round-robin blockIdx->XCD means each
//    XCD works on ONE batch = 4 planes = 4 MB = its L2 capacity; the 4x
//    overlapping-region re-reads then hit local L2, FETCH drops ~118->~35 MB).
//  - Non-temporal float4 stores: output is write-once streaming; keep it from
//    evicting the input working set out of L2.
// Row stride = 500 floats = 2000 B = 125*16 B -> every row start 16B-aligned;
// the 4-wide read is ONE aligned dwordx4 when colbase <= 496; colbase >= 500
// (tj==14, rc4>=13) is fully edge-clamped -> scalar load splat.

#define NB 8
#define NC 4
#define HW 500
#define RS 64
#define NT 15            // region starts per dim: 0,32,...,448
#define NREG (NT * NT)   // 225

typedef float f4 __attribute__((ext_vector_type(4)));

__global__ __launch_bounds__(256) void region_partition_kernel(
    const float* __restrict__ x, float* __restrict__ out) {
    int bx = blockIdx.x;             // 7200 blocks
    int b  = bx & 7;                 // XCD-aware: one batch per XCD
    int i  = bx >> 3;                // 0..899
    int c  = i & 3;
    int r  = i >> 2;                 // 0..224
    int ti = r / NT;
    int tj = r - ti * NT;

    int tid = threadIdx.x;
    int rc4 = tid & 15;              // float4 chunk within 64-wide row
    int rr0 = tid >> 4;              // 0..15

    int colbase = tj * 32 + rc4 * 4; // multiple of 4; <=496 or >=500
    const float* plane = x + (size_t)(b * NC + c) * (HW * HW);
    f4* dst = reinterpret_cast<f4*>(out)
            + (size_t)((b * NREG + r) * NC + c) * (RS * RS / 4);

    const bool clean = (colbase + 3 < HW);

    #pragma unroll
    for (int it = 0; it < 4; ++it) {
        int rr  = rr0 + 16 * it;
        int row = min(ti * 32 + rr, HW - 1);   // edge pad (replicate last row)
        const float* src = plane + (size_t)row * HW;
        f4 v;
        if (clean) {
            v = *reinterpret_cast<const f4*>(src + colbase);
        } else {
            float s = src[HW - 1];             // cols 500..511 all clamp to 499
            v = (f4){s, s, s, s};
        }
        __builtin_nontemporal_store(v, dst + rr * 16 + rc4);
    }
}

extern "C" void kernel_launch(void* const* d_in, const int* in_sizes, int n_in,
                              void* d_out, int out_size, void* d_ws, size_t ws_size,
                              hipStream_t stream) {
    const float* x = (const float*)d_in[0];
    float* out = (float*)d_out;

    const int grid = NB * NREG * NC;   // 7200 blocks, one region each
    region_partition_kernel<<<grid, 256, 0, stream>>>(x, out);
}

// Round 4
// 151.348 us; speedup vs baseline: 1.0367x; 1.0367x over previous
//
#include <hip/hip_runtime.h>

// RegionPartitioner: x (8,4,500,500) f32, step=32, region=64, edge-pad to 512.
// Out: (8, 225, 4, 64, 64) f32.  out[b,r,c,rr,rc] = x[b,c,min(32*(r/15)+rr,499),
//                                                      min(32*(r%15)+rc,499)]
//
// R3 = revert to R1 (best measured: 150.4 µs). R2's nt-stores + XCD swizzle
// were neutral/negative: input (32 MB) fits in L3, so L2-locality tricks don't
// change HBM traffic, and nt stores gain nothing for already-coalesced
// full-line writes.
//
// Structure: one block per region (b,r,c). 256 threads x 4 iters cover the
// 64x64 tile as 1024 float4 chunks. Row stride = 500 floats = 2000 B =
// 125*16 B, so every row start is 16B-aligned and the 4-wide read is ONE
// aligned dwordx4 when colbase <= 496. colbase >= 500 (tj==14, rc4>=13) is
// fully edge-clamped -> scalar load splat. Per-region math is wave-uniform.
// Floor: 118 MB write + 32 MB read ~= 24 µs @ 6.3 TB/s; VMEM-issue floor
// (1 load + 1 store dwordx4 per 16 B) coincides.

#define NB 8
#define NC 4
#define HW 500
#define RS 64
#define NT 15            // region starts per dim: 0,32,...,448
#define NREG (NT * NT)   // 225

__global__ __launch_bounds__(256) void region_partition_kernel(
    const float* __restrict__ x, float* __restrict__ out) {
    int bx = blockIdx.x;             // 0..7199 = (b*225 + r)*4 + c
    int c  = bx & 3;
    int br = bx >> 2;                // b*225 + r
    int b  = br / NREG;
    int r  = br - b * NREG;
    int ti = r / NT;
    int tj = r - ti * NT;

    int tid = threadIdx.x;
    int rc4 = tid & 15;              // float4 chunk within 64-wide row
    int rr0 = tid >> 4;              // 0..15

    int colbase = tj * 32 + rc4 * 4; // multiple of 4; <=496 or >=500
    const float* plane = x + (size_t)(b * NC + c) * (HW * HW);
    float4* dst = reinterpret_cast<float4*>(out)
                + (size_t)((b * NREG + r) * NC + c) * (RS * RS / 4);

    const bool clean = (colbase + 3 < HW);

    #pragma unroll
    for (int i = 0; i < 4; ++i) {
        int rr  = rr0 + 16 * i;
        int row = min(ti * 32 + rr, HW - 1);   // edge pad (replicate last row)
        const float* src = plane + (size_t)row * HW;
        float4 v;
        if (clean) {
            v = *reinterpret_cast<const float4*>(src + colbase);
        } else {
            float s = src[HW - 1];             // cols 500..511 all clamp to 499
            v = make_float4(s, s, s, s);
        }
        dst[rr * 16 + rc4] = v;                // wave: 64 consecutive float4s
    }
}

extern "C" void kernel_launch(void* const* d_in, const int* in_sizes, int n_in,
                              void* d_out, int out_size, void* d_ws, size_t ws_size,
                              hipStream_t stream) {
    const float* x = (const float*)d_in[0];
    float* out = (float*)d_out;

    const int grid = NB * NREG * NC;   // 7200 blocks, one region each
    region_partition_kernel<<<grid, 256, 0, stream>>>(x, out);
}